// Round 1
// baseline (280.610 us; speedup 1.0000x reference)
//
#include <hip/hip_runtime.h>

// BatchBlur: depthwise 15x15 cross-correlation, per-sample kernel, reflect pad.
// x: (32,3,512,512) f32, kernel: (32,15,15) f32, out: (32,3,512,512) f32.
//
// Tile plan: 128x64 output tile per block, 256 threads, 8x4 micro-tile/thread.
// Input slab (78 x 142) staged in LDS (stride 143 -> 44.6 KB, 3 blocks/CU).
// Row-reuse K-loop: each LDS row window (22 floats) feeds up to 480 FMAs.

#define HH 512
#define WW 512
#define LL 15
#define PP 7
#define TILE_W 128
#define TILE_H 64
#define SLAB_H (TILE_H + LL - 1)   // 78
#define SLAB_W (TILE_W + LL - 1)   // 142
#define SSTRIDE (SLAB_W + 1)       // 143 (odd, breaks pow2 bank stride)

__global__ __launch_bounds__(256, 3)
void batchblur_f32(const float* __restrict__ x,
                   const float* __restrict__ kern,
                   float* __restrict__ out)
{
    __shared__ float s[SLAB_H * SSTRIDE];

    const int tid   = threadIdx.x;
    const int ox0   = blockIdx.x * TILE_W;
    const int oy0   = blockIdx.y * TILE_H;
    const int plane = blockIdx.z;           // b*3 + c
    const int b     = plane / 3;

    const float* __restrict__ xp = x + (size_t)plane * (HH * WW);
    const float* __restrict__ kp = kern + b * (LL * LL);   // block-uniform -> s_load

    // ---- stage input slab (reflect padding resolved here) into LDS ----
    for (int i = tid; i < SLAB_H * SLAB_W; i += 256) {
        int r    = i / SLAB_W;
        int ccol = i - r * SLAB_W;
        int gy = oy0 + r - PP;
        int gx = ox0 + ccol - PP;
        gy = (gy < 0) ? -gy : gy;
        gy = (gy >= HH) ? (2 * HH - 2 - gy) : gy;
        gx = (gx < 0) ? -gx : gx;
        gx = (gx >= WW) ? (2 * WW - 2 - gx) : gx;
        s[r * SSTRIDE + ccol] = xp[gy * WW + gx];
    }
    __syncthreads();

    const int tx      = tid & 15;   // 16 threads x 8 cols = 128 wide
    const int ty      = tid >> 4;   // 16 threads x 4 rows = 64 tall
    const int row0    = ty * 4;     // output-row offset within tile
    const int colbase = tx * 8;

    float acc[4][8];
    #pragma unroll
    for (int dy = 0; dy < 4; ++dy)
        #pragma unroll
        for (int i = 0; i < 8; ++i) acc[dy][i] = 0.f;

    // Input slab rows used by this thread: row0 .. row0+17 (4 out rows + 14 halo)
    #pragma unroll 1
    for (int rr = 0; rr < TILE_H / 16 + LL - 1; ++rr) {   // 18 iterations
        float w[22];
        const float* srow = &s[(row0 + rr) * SSTRIDE + colbase];
        #pragma unroll
        for (int j = 0; j < 22; ++j) w[j] = srow[j];

        #pragma unroll
        for (int dy = 0; dy < 4; ++dy) {
            const int ky = rr - dy;            // uniform; guard is a scalar branch
            if (ky >= 0 && ky < LL) {
                #pragma unroll
                for (int kx = 0; kx < LL; ++kx) {
                    const float kv = kp[ky * LL + kx];   // uniform -> SGPR operand
                    #pragma unroll
                    for (int i = 0; i < 8; ++i)
                        acc[dy][i] = fmaf(kv, w[kx + i], acc[dy][i]);
                }
            }
        }
    }

    // ---- store 8x4 micro-tile, two float4 per row ----
    float* __restrict__ op = out + (size_t)plane * (HH * WW);
    #pragma unroll
    for (int dy = 0; dy < 4; ++dy) {
        float* dst = op + (size_t)(oy0 + row0 + dy) * WW + ox0 + colbase;
        float4 v0 = make_float4(acc[dy][0], acc[dy][1], acc[dy][2], acc[dy][3]);
        float4 v1 = make_float4(acc[dy][4], acc[dy][5], acc[dy][6], acc[dy][7]);
        reinterpret_cast<float4*>(dst)[0] = v0;
        reinterpret_cast<float4*>(dst)[1] = v1;
    }
}

extern "C" void kernel_launch(void* const* d_in, const int* in_sizes, int n_in,
                              void* d_out, int out_size, void* d_ws, size_t ws_size,
                              hipStream_t stream) {
    const float* x  = (const float*)d_in[0];
    const float* kn = (const float*)d_in[1];
    float* out      = (float*)d_out;
    dim3 grid(WW / TILE_W, HH / TILE_H, 32 * 3);   // (4, 8, 96)
    batchblur_f32<<<grid, dim3(256), 0, stream>>>(x, kn, out);
}

// Round 2
// 220.587 us; speedup vs baseline: 1.2721x; 1.2721x over previous
//
#include <hip/hip_runtime.h>

// BatchBlur via bf16 MFMA banded-Toeplitz.
// out[16s+m] = sum_kx K[ky][kx] * pad[y+ky][16s+m+kx]
//  -> D = A(ky) * B(ky,row-set,seg), A[m][k] = K[ky][k-m] (banded 16x32),
//     B[k][n] = staged_row[g*16+n+ky][16s+k], accumulate C over ky=0..14.
// Fragment layouts (gfx950, HW-verified per guide):
//  A: m=lane&15, k=quad*8+j ; B: n=lane&15, k=quad*8+j ; D: n=lane&15, m=quad*4+reg.

#define HH 512
#define WW 512
#define LL 15
#define PP 7
#define TW 128                    // output tile width per block
#define TH 64                     // output tile height per block
#define SH (TH + LL - 1)          // 78 staged rows
#define SWB 152                   // staged row width in bf16 (>=144, 16B-aligned rows)
#define KPAD 64                   // padded kernel-row buffer (zeros outside [16,31))

typedef __attribute__((ext_vector_type(8))) short bf16x8;
typedef __attribute__((ext_vector_type(4))) float f32x4;

__device__ inline unsigned short f2bf(float f) {
    unsigned u = __builtin_bit_cast(unsigned, f);
    unsigned r = (u + 0x7fffu + ((u >> 16) & 1u)) >> 16;   // RNE
    return (unsigned short)r;
}

__global__ __launch_bounds__(256, 4)
void batchblur_mfma(const float* __restrict__ x,
                    const float* __restrict__ kern,
                    float* __restrict__ out)
{
    __shared__ unsigned short sx[SH * SWB];   // 23712 B
    __shared__ unsigned short sk[LL * KPAD];  // 1920 B zero-padded kernel rows

    const int tid   = threadIdx.x;
    const int ox0   = blockIdx.x * TW;
    const int oy0   = blockIdx.y * TH;
    const int plane = blockIdx.z;             // b*3 + c
    const int b     = plane / 3;

    const float* __restrict__ xp = x + (size_t)plane * (HH * WW);
    const float* __restrict__ kp = kern + b * (LL * LL);

    // ---- stage kernel rows, zero-padded, as bf16 ----
    for (int i = tid; i < LL * KPAD; i += 256) {
        int ky = i / KPAD, c = i - ky * KPAD;
        float v = (c >= 16 && c < 16 + LL) ? kp[ky * LL + (c - 16)] : 0.f;
        sk[i] = f2bf(v);
    }
    // ---- stage reflect-padded input slab as bf16 ----
    for (int i = tid; i < SH * SWB; i += 256) {
        int r = i / SWB, c = i - r * SWB;
        int gy = oy0 + r - PP;
        int gx = ox0 + c - PP;
        gy = gy < 0 ? -gy : (gy >= HH ? 2 * HH - 2 - gy : gy);
        gx = gx < 0 ? -gx : (gx >= WW ? 2 * WW - 2 - gx : gx);
        sx[i] = f2bf(xp[gy * WW + gx]);
    }
    __syncthreads();

    const int lane = tid & 63;
    const int t    = lane & 15;   // A row m / B-D col n
    const int q    = lane >> 2 >> 2;  // quad = lane>>4
    const int g    = tid >> 6;    // wave id -> row group (4 groups x 16 rows)

    // ---- build banded A fragments, one per ky (held in VGPRs) ----
    bf16x8 afrag[LL];
    #pragma unroll
    for (int ky = 0; ky < LL; ++ky) {
        bf16x8 a;
        #pragma unroll
        for (int j = 0; j < 8; ++j)
            a[j] = (short)sk[ky * KPAD + 16 + q * 8 + j - t];   // idx in [1, 944)
        afrag[ky] = a;
    }

    float* __restrict__ op = out + (size_t)plane * (HH * WW);
    const int rowbase = g * 16 + t;

    // ---- 8 segments, processed as 4 pairs for MFMA ILP ----
    #pragma unroll 1
    for (int s2 = 0; s2 < 4; ++s2) {
        const int sA = s2, sB = s2 + 4;
        f32x4 cA = {0.f, 0.f, 0.f, 0.f};
        f32x4 cB = {0.f, 0.f, 0.f, 0.f};
        #pragma unroll
        for (int ky = 0; ky < LL; ++ky) {
            const unsigned short* row = &sx[(rowbase + ky) * SWB];
            bf16x8 bA = *(const bf16x8*)&row[sA * 16 + q * 8];
            bf16x8 bB = *(const bf16x8*)&row[sB * 16 + q * 8];
            cA = __builtin_amdgcn_mfma_f32_16x16x32_bf16(afrag[ky], bA, cA, 0, 0, 0);
            cB = __builtin_amdgcn_mfma_f32_16x16x32_bf16(afrag[ky], bB, cB, 0, 0, 0);
        }
        const int y = oy0 + rowbase;
        float* dA = op + (size_t)y * WW + ox0 + sA * 16 + q * 4;
        float* dB = op + (size_t)y * WW + ox0 + sB * 16 + q * 4;
        *(float4*)dA = make_float4(cA[0], cA[1], cA[2], cA[3]);
        *(float4*)dB = make_float4(cB[0], cB[1], cB[2], cB[3]);
    }
}

extern "C" void kernel_launch(void* const* d_in, const int* in_sizes, int n_in,
                              void* d_out, int out_size, void* d_ws, size_t ws_size,
                              hipStream_t stream) {
    const float* x  = (const float*)d_in[0];
    const float* kn = (const float*)d_in[1];
    float* out      = (float*)d_out;
    dim3 grid(WW / TW, HH / TH, 32 * 3);   // (4, 8, 96)
    batchblur_mfma<<<grid, dim3(256), 0, stream>>>(x, kn, out);
}

// Round 4
// 200.030 us; speedup vs baseline: 1.4028x; 1.1028x over previous
//
#include <hip/hip_runtime.h>

// BatchBlur via bf16 MFMA banded-Toeplitz. R4 = R3 with the A-build funnel
// shift FIXED: align to 4B (shift in {0,16}) instead of 16B (shift up to 112,
// which broke the 32-bit funnel pairs).
// D = A(ky)*B: A[m][k] = K[ky][k-m] banded 16x32, B[k][n] = slab rows,
// C accumulates over ky. Layouts (gfx950, HW-verified per guide):
// A: m=lane&15,k=q*8+j ; B: n=lane&15,k=q*8+j ; D: n=lane&15, m=q*4+reg.

#define HH 512
#define WW 512
#define LL 15
#define PP 7
#define TW 128
#define TH 64
#define SH (TH + LL - 1)          // 78
#define SWB 152                   // slab row in bf16 elems; 304B rows, 16B-aligned
#define KPAD 64                   // kernel row pad (128B)
#define NSEG 8

typedef __attribute__((ext_vector_type(8))) short bf16x8;
typedef __attribute__((ext_vector_type(4))) float f32x4;

__device__ inline unsigned short f2bf(float f) {
    unsigned u = __builtin_bit_cast(unsigned, f);
    return (unsigned short)((u + 0x7fffu + ((u >> 16) & 1u)) >> 16);   // RNE
}

__global__ __launch_bounds__(256, 5)
void batchblur_mfma(const float* __restrict__ x,
                    const float* __restrict__ kern,
                    float* __restrict__ out)
{
    __shared__ unsigned short sx[SH * SWB];   // 23712 B
    __shared__ unsigned short sk[LL * KPAD];  // 1920 B

    const int tid   = threadIdx.x;
    const int ox0   = blockIdx.x * TW;
    const int oy0   = blockIdx.y * TH;
    const int plane = blockIdx.z;
    const int b     = plane / 3;

    const float* __restrict__ xp = x + (size_t)plane * (HH * WW);
    const float* __restrict__ kp = kern + b * (LL * LL);

    // ---- stage zero-padded kernel rows (bf16) ----
    for (int i = tid; i < LL * KPAD; i += 256) {
        int ky = i >> 6, c = i & 63;
        float v = (c >= 16 && c < 16 + LL) ? kp[ky * LL + (c - 16)] : 0.f;
        sk[i] = f2bf(v);
    }

    // ---- stage reflect-padded slab, 4 cols/thread, ds_write_b64 ----
    for (int i = tid; i < SH * (SWB / 4); i += 256) {
        int r  = i / (SWB / 4);
        int c4 = (i - r * (SWB / 4)) * 4;
        int gy = oy0 + r - PP;
        gy = gy < 0 ? -gy : (gy >= HH ? 2 * HH - 2 - gy : gy);
        const float* __restrict__ rowp = xp + (size_t)gy * WW;
        unsigned short h[4];
        #pragma unroll
        for (int j = 0; j < 4; ++j) {
            int gx = ox0 + c4 + j - PP;
            gx = gx < 0 ? -gx : (gx >= WW ? 2 * WW - 2 - gx : gx);
            h[j] = f2bf(rowp[gx]);
        }
        uint2 pk;
        pk.x = (unsigned)h[0] | ((unsigned)h[1] << 16);
        pk.y = (unsigned)h[2] | ((unsigned)h[3] << 16);
        *(uint2*)&sx[r * SWB + c4] = pk;
    }
    __syncthreads();

    const int lane = tid & 63;
    const int t    = lane & 15;       // A row m / B-D col n
    const int q    = lane >> 4;       // quad
    const int g    = tid >> 6;        // wave -> 16-row group
    const int rowbase = g * 16 + t;

    f32x4 acc[NSEG];
    #pragma unroll
    for (int s = 0; s < NSEG; ++s) acc[s] = (f32x4){0.f, 0.f, 0.f, 0.f};

    // A-build geometry (loop-invariant): elements e..e+7 of padded kernel row.
    // byte offset b0 = 2e is even; align to 4B so funnel shift is 0 or 16 bits.
    const int e    = 16 + q * 8 - t;  // in [1, 40]
    const int b0   = 2 * e;           // in [2, 80]
    const int base = (b0 & ~3) >> 2;  // dword index, in [0, 20]; base+4 <= 24 < 32
    const int sh   = (b0 & 3) * 8;    // 0 or 16

    #pragma unroll 1
    for (int ky = 0; ky < LL; ++ky) {
        // ---- banded A fragment via 4B-aligned reads + 32-bit funnels ----
        const int* rp = (const int*)&sk[ky * KPAD];
        int v[5];
        #pragma unroll
        for (int j = 0; j < 5; ++j) v[j] = rp[base + j];
        int r32[4];
        #pragma unroll
        for (int j = 0; j < 4; ++j)
            r32[j] = (int)(unsigned)(((((unsigned long long)(unsigned)v[j + 1]) << 32)
                                      | (unsigned)v[j]) >> sh);
        bf16x8 afrag = __builtin_bit_cast(bf16x8, (int4){r32[0], r32[1], r32[2], r32[3]});

        const unsigned short* srow = &sx[(rowbase + ky) * SWB + q * 8];
        // ---- 8 segments, two groups of 4 to bound live B-frags ----
        bf16x8 bf[4];
        #pragma unroll
        for (int s = 0; s < 4; ++s) bf[s] = *(const bf16x8*)&srow[s * 16];
        #pragma unroll
        for (int s = 0; s < 4; ++s)
            acc[s] = __builtin_amdgcn_mfma_f32_16x16x32_bf16(afrag, bf[s], acc[s], 0, 0, 0);
        #pragma unroll
        for (int s = 0; s < 4; ++s) bf[s] = *(const bf16x8*)&srow[(s + 4) * 16];
        #pragma unroll
        for (int s = 0; s < 4; ++s)
            acc[s + 4] = __builtin_amdgcn_mfma_f32_16x16x32_bf16(afrag, bf[s], acc[s + 4], 0, 0, 0);
    }

    // ---- store: 8 x float4, D layout n=lane&15 (row), m=q*4+reg (col) ----
    float* __restrict__ op = out + (size_t)plane * (HH * WW) + (size_t)(oy0 + rowbase) * WW + ox0;
    #pragma unroll
    for (int s = 0; s < NSEG; ++s) {
        float* dst = op + s * 16 + q * 4;
        *(float4*)dst = make_float4(acc[s][0], acc[s][1], acc[s][2], acc[s][3]);
    }
}

extern "C" void kernel_launch(void* const* d_in, const int* in_sizes, int n_in,
                              void* d_out, int out_size, void* d_ws, size_t ws_size,
                              hipStream_t stream) {
    const float* x  = (const float*)d_in[0];
    const float* kn = (const float*)d_in[1];
    float* out      = (float*)d_out;
    dim3 grid(WW / TW, HH / TH, 32 * 3);   // (4, 8, 96)
    batchblur_mfma<<<grid, dim3(256), 0, stream>>>(x, kn, out);
}